// Round 12
// baseline (2770.290 us; speedup 1.0000x reference)
//
#include <hip/hip_runtime.h>
#include <hip/hip_bf16.h>

#define BATCH 1024
#define HD 256
#define MLEN 80
#define LPRE 60
#define LFWD 80
#define KIN 32
#define KOUT 16

typedef unsigned short bf16_t;
typedef __attribute__((ext_vector_type(8))) short bf16x8;
typedef __attribute__((ext_vector_type(4))) float f32x4;
typedef __attribute__((ext_vector_type(4))) unsigned u32x4;

#define MFMA __builtin_amdgcn_mfma_f32_16x16x32_bf16

__device__ __forceinline__ float bf2f(bf16_t v){ return __uint_as_float(((unsigned)v)<<16); }
__device__ __forceinline__ bf16_t f2bf(float f){
    unsigned u = __float_as_uint(f);
    return (bf16_t)((u + 0x7FFFu + ((u>>16)&1u)) >> 16);
}
__device__ __forceinline__ unsigned pack2(float lo, float hi){
    return (unsigned)f2bf(lo) | ((unsigned)f2bf(hi)<<16);
}
__device__ __forceinline__ float bflo(unsigned d){ return __uint_as_float(d<<16); }
__device__ __forceinline__ float bfhi(unsigned d){ return __uint_as_float(d & 0xffff0000u); }
__device__ __forceinline__ float sigm(float x){ return 1.0f/(1.0f+__expf(-x)); }

// Packed-B byte offsets inside a GRU weight pack (4 N-groups):
#define OFF_Z  262144
#define OFF_IN 524288
#define OFF_HN 655360

// ---------------------------------------------------------------------------
// Pack GRU weights: B[k][n] fragment-tiled bf16. grid 192x256
// ---------------------------------------------------------------------------
__global__ void pack_gru(const float* __restrict__ Wih, const float* __restrict__ Whh,
                         bf16_t* __restrict__ dst)
{
    int T = blockIdx.x*256 + threadIdx.x;   // < 49152
    int grp, local;
    if (T < 16384){ grp=0; local=T; }
    else if (T < 32768){ grp=1; local=T-16384; }
    else if (T < 40960){ grp=2; local=T-32768; }
    else { grp=3; local=T-40960; }
    int nkt = (grp<2)?16:8;
    int nt  = local / (nkt*64);
    int rem = local - nt*(nkt*64);
    int kt  = rem >> 6;
    int l   = rem & 63;
    int n   = nt*16 + (l&15);
    int k0  = kt*32 + ((l>>4)<<3);
    unsigned w[4];
    #pragma unroll
    for (int h2=0; h2<4; h2++){
        float v[2];
        #pragma unroll
        for (int s=0; s<2; s++){
            int k = k0 + h2*2 + s;
            if (grp==0)      v[s] = (k<256)? Wih[(size_t)n*HD + k]       : Whh[(size_t)n*HD + (k-256)];
            else if (grp==1) v[s] = (k<256)? Wih[(size_t)(256+n)*HD + k] : Whh[(size_t)(256+n)*HD + (k-256)];
            else if (grp==2) v[s] = Wih[(size_t)(512+n)*HD + k];
            else             v[s] = Whh[(size_t)(512+n)*HD + k];
        }
        w[h2] = pack2(v[0], v[1]);
    }
    uint4 u = {w[0],w[1],w[2],w[3]};
    *(uint4*)((char*)dst + (size_t)T*16) = u;
}

// ---------------------------------------------------------------------------
// Pack K=512,N=256 B from W[256][512] (combW): B[k][n]=W[n][k]. grid 64x256
// ---------------------------------------------------------------------------
__global__ void pack_B512(const float* __restrict__ W, bf16_t* __restrict__ dst)
{
    int T = blockIdx.x*256 + threadIdx.x;   // < 16384
    int nt = T >> 10, kt = (T>>6)&15, l = T&63;
    int n = nt*16 + (l&15);
    int k0 = kt*32 + ((l>>4)<<3);
    unsigned w[4];
    #pragma unroll
    for (int h2=0; h2<4; h2++)
        w[h2] = pack2(W[(size_t)n*512 + k0+h2*2], W[(size_t)n*512 + k0+h2*2+1]);
    uint4 u = {w[0],w[1],w[2],w[3]};
    *(uint4*)((char*)dst + (size_t)T*16) = u;
}

// ---------------------------------------------------------------------------
// Wfuse[k][n] = sum_o dembW[n][o]*outW[o][k]; e_bias[n]=dembB[n]+sum_o outB[o]*dembW[n][o]
// grid 257x256
// ---------------------------------------------------------------------------
__global__ void wfuse_kernel(const float* __restrict__ dembW, const float* __restrict__ dembB,
                             const float* __restrict__ outW, const float* __restrict__ outB,
                             float* __restrict__ Wfuse, float* __restrict__ ebias)
{
    int T = blockIdx.x*256 + threadIdx.x;
    if (T < 65536){
        int k = T >> 8, n = T & 255;
        float acc = 0.f;
        #pragma unroll
        for (int o=0;o<16;o++) acc += dembW[(size_t)n*48 + o]*outW[(size_t)o*HD + k];
        Wfuse[(size_t)k*HD + n] = acc;
    } else if (T < 65792){
        int n = T - 65536;
        float acc = dembB[n];
        #pragma unroll
        for (int o=0;o<16;o++) acc += outB[o]*dembW[(size_t)n*48 + o];
        ebias[n] = acc;
    }
}

// ---------------------------------------------------------------------------
// Pack logits B (t>=1 and t==0 variants) + bias vectors. grid 24x256.
// v11: loop-swapped + float4-vectorized (verified round 11).
// ---------------------------------------------------------------------------
__global__ void pack_logits(const float* __restrict__ Wfuse, const float* __restrict__ dembW,
                            const float* __restrict__ attW, const float* __restrict__ attB,
                            const float* __restrict__ dembB, const float* __restrict__ ebias,
                            bf16_t* __restrict__ BL, bf16_t* __restrict__ BL0,
                            float* __restrict__ lb, float* __restrict__ lb0)
{
    int T = blockIdx.x*256 + threadIdx.x;
    if (T < 5760){
        int variant = (T < 2880) ? 0 : 1;
        int local = variant ? (T-2880) : T;
        int nt = local/576, rem = local - nt*576;
        int kt = rem >> 6, l = rem & 63;
        int m  = nt*16 + (l&15);
        int k0 = kt*32 + ((l>>4)<<3);
        float acc[8];
        if (kt < 8){
            #pragma unroll
            for (int d=0;d<8;d++) acc[d] = attW[(size_t)m*512 + 256 + k0 + d];
            if (variant == 0){
                const float* ar = attW + (size_t)m*512;
                for (int n=0;n<256;n+=4){
                    float4 w = *(const float4*)(ar + n);
                    #pragma unroll
                    for (int d=0;d<8;d++){
                        float4 f = *(const float4*)(Wfuse + (size_t)(k0+d)*HD + n);
                        acc[d] = fmaf(f.x, w.x, acc[d]);
                        acc[d] = fmaf(f.y, w.y, acc[d]);
                        acc[d] = fmaf(f.z, w.z, acc[d]);
                        acc[d] = fmaf(f.w, w.w, acc[d]);
                    }
                }
            }
        } else {
            int kp0 = k0 - 256;
            #pragma unroll
            for (int d=0;d<8;d++) acc[d] = 0.f;
            const float* ar = attW + (size_t)m*512;
            for (int n=0;n<256;n++){
                float w = ar[n];
                const float* dr = dembW + (size_t)n*48 + 16 + kp0;
                float4 d0 = *(const float4*)dr;
                float4 d1 = *(const float4*)(dr+4);
                acc[0]=fmaf(d0.x,w,acc[0]); acc[1]=fmaf(d0.y,w,acc[1]);
                acc[2]=fmaf(d0.z,w,acc[2]); acc[3]=fmaf(d0.w,w,acc[3]);
                acc[4]=fmaf(d1.x,w,acc[4]); acc[5]=fmaf(d1.y,w,acc[5]);
                acc[6]=fmaf(d1.z,w,acc[6]); acc[7]=fmaf(d1.w,w,acc[7]);
            }
        }
        unsigned w4[4];
        #pragma unroll
        for (int h2=0;h2<4;h2++) w4[h2] = pack2(acc[h2*2], acc[h2*2+1]);
        uint4 u = {w4[0],w4[1],w4[2],w4[3]};
        bf16_t* d = variant ? BL0 : BL;
        *(uint4*)((char*)d + (size_t)local*16) = u;
    } else if (T < 5840){
        int m = T - 5760;
        float acc = attB[m];
        const float* ar = attW + (size_t)m*512;
        for (int n=0;n<256;n+=4){
            float4 w = *(const float4*)(ar + n);
            float4 e = *(const float4*)(ebias + n);
            acc = fmaf(e.x,w.x,acc); acc = fmaf(e.y,w.y,acc);
            acc = fmaf(e.z,w.z,acc); acc = fmaf(e.w,w.w,acc);
        }
        lb[m] = acc;
    } else if (T < 5920){
        int m = T - 5840;
        float acc = attB[m];
        const float* ar = attW + (size_t)m*512;
        for (int n=0;n<256;n+=4){
            float4 w = *(const float4*)(ar + n);
            float4 e = *(const float4*)(dembB + n);
            acc = fmaf(e.x,w.x,acc); acc = fmaf(e.y,w.y,acc);
            acc = fmaf(e.z,w.z,acc); acc = fmaf(e.w,w.w,acc);
        }
        lb0[m] = acc;
    }
}

// ---------------------------------------------------------------------------
// pack_gfold: Bgf[k][n] (K=288, 9 kt x 16 nt) = Be_src @ W1, fragment-packed.
// v11: loop-swapped + float4-vectorized (verified round 11).
// ---------------------------------------------------------------------------
__global__ void pack_gfold(const float* __restrict__ Wfuse, const float* __restrict__ dembW,
                           const float* __restrict__ combW, const float* __restrict__ combB,
                           const float* __restrict__ ebias, const float* __restrict__ dembB,
                           bf16_t* __restrict__ dst, float* __restrict__ cbf, float* __restrict__ cbf0)
{
    int T = blockIdx.x*256 + threadIdx.x;
    if (T < 9216){
        int nt = T/576, rem = T - nt*576;
        int kt = rem >> 6, l = rem & 63;
        int n = nt*16 + (l&15);
        int k0 = kt*32 + ((l>>4)<<3);
        float acc[8];
        #pragma unroll
        for (int d=0;d<8;d++) acc[d] = 0.f;
        const float* wr = combW + (size_t)n*512;
        if (kt < 8){
            for (int j=0;j<256;j+=4){
                float4 w = *(const float4*)(wr + j);
                #pragma unroll
                for (int d=0;d<8;d++){
                    float4 f = *(const float4*)(Wfuse + (size_t)(k0+d)*HD + j);
                    acc[d] = fmaf(f.x, w.x, acc[d]);
                    acc[d] = fmaf(f.y, w.y, acc[d]);
                    acc[d] = fmaf(f.z, w.z, acc[d]);
                    acc[d] = fmaf(f.w, w.w, acc[d]);
                }
            }
        } else {
            int kp0 = k0 - 256;
            for (int j=0;j<256;j++){
                float w = wr[j];
                const float* dr = dembW + (size_t)j*48 + 16 + kp0;
                float4 d0 = *(const float4*)dr;
                float4 d1 = *(const float4*)(dr+4);
                acc[0]=fmaf(d0.x,w,acc[0]); acc[1]=fmaf(d0.y,w,acc[1]);
                acc[2]=fmaf(d0.z,w,acc[2]); acc[3]=fmaf(d0.w,w,acc[3]);
                acc[4]=fmaf(d1.x,w,acc[4]); acc[5]=fmaf(d1.y,w,acc[5]);
                acc[6]=fmaf(d1.z,w,acc[6]); acc[7]=fmaf(d1.w,w,acc[7]);
            }
        }
        unsigned w4[4];
        #pragma unroll
        for (int h2=0;h2<4;h2++) w4[h2] = pack2(acc[h2*2], acc[h2*2+1]);
        uint4 u = {w4[0],w4[1],w4[2],w4[3]};
        *(uint4*)((char*)dst + (size_t)T*16) = u;
    } else if (T < 9472){
        int n = T - 9216;
        float acc = combB[n];
        const float* wr = combW + (size_t)n*512;
        for (int j=0;j<256;j+=4){
            float4 w = *(const float4*)(wr + j);
            float4 e = *(const float4*)(ebias + j);
            acc = fmaf(e.x,w.x,acc); acc = fmaf(e.y,w.y,acc);
            acc = fmaf(e.z,w.z,acc); acc = fmaf(e.w,w.w,acc);
        }
        cbf[n] = acc;
    } else if (T < 9728){
        int n = T - 9472;
        float acc = combB[n];
        const float* wr = combW + (size_t)n*512;
        for (int j=0;j<256;j+=4){
            float4 w = *(const float4*)(wr + j);
            float4 e = *(const float4*)(dembB + j);
            acc = fmaf(e.x,w.x,acc); acc = fmaf(e.y,w.y,acc);
            acc = fmaf(e.z,w.z,acc); acc = fmaf(e.w,w.w,acc);
        }
        cbf0[n] = acc;
    }
}

// ---------------------------------------------------------------------------
// Pack B_out [K=256][N=16] from outW[16][256]. grid 2x256
// ---------------------------------------------------------------------------
__global__ void pack_out(const float* __restrict__ outW, bf16_t* __restrict__ dst)
{
    int T = blockIdx.x*256 + threadIdx.x;   // < 512
    int kt = T >> 6, l = T & 63;
    int n  = l & 15;
    int k0 = kt*32 + ((l>>4)<<3);
    unsigned w[4];
    #pragma unroll
    for (int h2=0; h2<4; h2++)
        w[h2] = pack2(outW[(size_t)n*HD + k0+h2*2], outW[(size_t)n*HD + k0+h2*2+1]);
    uint4 u = {w[0],w[1],w[2],w[3]};
    *(uint4*)((char*)dst + (size_t)T*16) = u;
}

// ---------------------------------------------------------------------------
// All 60 encoder embeddings -> bf16. grid (64,60)x256
// ---------------------------------------------------------------------------
__global__ __launch_bounds__(256) void emb_kernel(
    const float* __restrict__ px, const float* __restrict__ py,
    const float* __restrict__ embW, const float* __restrict__ embB,
    bf16_t* __restrict__ emb)
{
    __shared__ float Ws[256*49];
    __shared__ float xy[16][48];
    __shared__ float bs[256];
    int t = blockIdx.y, b0 = blockIdx.x*16, tid = threadIdx.x;
    for (int i = tid; i < 256*48; i += 256){ int n=i/48, k=i-n*48; Ws[n*49+k]=embW[i]; }
    bs[tid] = embB[tid];
    for (int i = tid; i < 16*48; i += 256){
        int r=i/48, k=i-r*48;
        xy[r][k] = (k<KIN)? px[((size_t)t*BATCH + b0+r)*KIN + k]
                          : py[((size_t)t*BATCH + b0+r)*KOUT + (k-KIN)];
    }
    __syncthreads();
    int n = tid;
    const float* w = &Ws[n*49];
    for (int r=0;r<16;r++){
        float acc = bs[n];
        #pragma unroll
        for (int k=0;k<48;k++) acc += xy[r][k]*w[k];
        emb[((size_t)t*BATCH + b0+r)*HD + n] = f2bf(acc);
    }
}

// fx f32 -> bf16. grid 1280x256
__global__ void fxconv(const float* __restrict__ fx, bf16_t* __restrict__ dst)
{
    size_t i = (size_t)blockIdx.x*256 + threadIdx.x;
    const float4* s = (const float4*)(fx + i*8);
    float4 a = s[0], b = s[1];
    uint4 u = { pack2(a.x,a.y), pack2(a.z,a.w), pack2(b.x,b.y), pack2(b.z,b.w) };
    *(uint4*)(dst + i*8) = u;
}

// ---------------------------------------------------------------------------
// enc_persist: ALL 60 encoder GRU steps in ONE dispatch. 64 blocks x 1024
// threads (16 waves = 16 jt tiles). h lives in LDS (f32 + bf16) across steps;
// batch rows are block-local -> ZERO inter-block communication. Weights
// (768 KB) stay L2-resident per XCD. Math identical to verified gru path.
// ---------------------------------------------------------------------------
__global__ __launch_bounds__(1024) void enc_persist(
    const bf16_t* __restrict__ EMB, const bf16_t* __restrict__ Bp,
    const float* __restrict__ bih, const float* __restrict__ bhh,
    float* __restrict__ hf_out, bf16_t* __restrict__ hb_out,
    bf16_t* __restrict__ enc_out)
{
    __shared__ __align__(16) bf16_t Xb[16][264];
    __shared__ __align__(16) bf16_t Hb[16][264];
    __shared__ float Hf[16][260];
    int tid = threadIdx.x, b0 = blockIdx.x*16;
    int lane = tid & 63, wave = tid >> 6;   // wave == jt (0..15)
    size_t loff = (size_t)lane*16;
    const char* bpc = (const char*)Bp;

    for (int i = tid; i < 16*264; i += 1024) ((bf16_t*)Hb)[i] = 0;
    for (int i = tid; i < 16*260; i += 1024) ((float*)Hf)[i] = 0.f;
    if (tid < 512){
        int r = tid >> 5, c0 = (tid & 31)*8;
        *(uint4*)&Xb[r][c0] = *(const uint4*)&EMB[((size_t)0*BATCH + b0+r)*HD + c0];
    }
    __syncthreads();

    int jt = wave;
    int j = (jt<<4) + (lane&15);
    float b_r = bih[j] + bhh[j];
    float b_z = bih[256+j] + bhh[256+j];
    float b_i = bih[512+j], b_h = bhh[512+j];
    const bf16_t* ar = &Xb[lane&15][(lane>>4)*8];
    const bf16_t* ah = &Hb[lane&15][(lane>>4)*8];

    #pragma unroll 1
    for (int t = 0; t < LPRE; t++){
        f32x4 cr={0,0,0,0}, cz={0,0,0,0}, ci={0,0,0,0}, ch={0,0,0,0};
        #pragma unroll
        for (int kt=0; kt<16; kt++){
            bf16x8 a = (kt<8)? *(const bf16x8*)(ar + kt*32)
                             : *(const bf16x8*)(ah + (kt-8)*32);
            bf16x8 br = *(const bf16x8*)(bpc + (size_t)(((jt<<4)+kt)<<10) + loff);
            bf16x8 bz = *(const bf16x8*)(bpc + OFF_Z + (size_t)(((jt<<4)+kt)<<10) + loff);
            cr = MFMA(a, br, cr, 0,0,0);
            cz = MFMA(a, bz, cz, 0,0,0);
            if (kt < 8){
                bf16x8 bi = *(const bf16x8*)(bpc + OFF_IN + (size_t)(((jt<<3)+kt)<<10) + loff);
                ci = MFMA(a, bi, ci, 0,0,0);
            } else {
                bf16x8 bh2 = *(const bf16x8*)(bpc + OFF_HN + (size_t)(((jt<<3)+kt-8)<<10) + loff);
                ch = MFMA(a, bh2, ch, 0,0,0);
            }
        }
        __syncthreads();
        #pragma unroll
        for (int q=0;q<4;q++){
            int r = ((lane>>4)<<2) + q;
            float rv = sigm(cr[q] + b_r);
            float zv = sigm(cz[q] + b_z);
            float nv = tanhf(ci[q] + b_i + rv*(ch[q] + b_h));
            float h2 = (1.0f - zv)*nv + zv*Hf[r][j];
            Hf[r][j] = h2;
            Hb[r][j] = f2bf(h2);
        }
        __syncthreads();
        if (tid < 512){
            int r = tid >> 5, c0 = (tid & 31)*8;
            *(uint4*)(enc_out + ((size_t)t*BATCH + b0+r)*HD + c0) = *(const uint4*)&Hb[r][c0];
            if (t+1 < LPRE)
                *(uint4*)&Xb[r][c0] = *(const uint4*)&EMB[((size_t)(t+1)*BATCH + b0+r)*HD + c0];
        }
        __syncthreads();
    }

    // final h -> global (for decoder start)
    if (tid < 512){
        int r = tid >> 5, c0 = (tid & 31)*8;
        *(uint4*)&hb_out[(size_t)(b0+r)*HD + c0] = *(const uint4*)&Hb[r][c0];
    }
    {
        int r = tid >> 6, c0 = (tid & 63)*4;
        float4 v = {Hf[r][c0], Hf[r][c0+1], Hf[r][c0+2], Hf[r][c0+3]};
        *(float4*)&hf_out[(size_t)(b0+r)*HD + c0] = v;
    }
}

// ---------------------------------------------------------------------------
// pgemm: P[t][b][n] = ENC_OUT[t][b][:] @ W2  (W2 = PACK_CMB kt 8..15).
// grid (64,60) x 256. (verified round 7/8)
// ---------------------------------------------------------------------------
__global__ __launch_bounds__(256) void pgemm(
    const bf16_t* __restrict__ enc, const bf16_t* __restrict__ Bcmb,
    bf16_t* __restrict__ P)
{
    __shared__ __align__(16) bf16_t As[16][264];
    __shared__ __align__(16) bf16_t Gs[16][264];
    int tid = threadIdx.x, b0 = blockIdx.x*16, t = blockIdx.y;
    const bf16_t* src = enc + ((size_t)t*BATCH + b0)*HD;
    for (int i = tid; i < 512; i += 256){
        int r = i>>5, c = i&31;
        *(uint4*)&As[r][c*8] = *(const uint4*)(src + (size_t)r*HD + c*8);
    }
    __syncthreads();
    int lane = tid&63, wave = tid>>6;
    const bf16_t* arow = &As[lane&15][(lane>>4)*8];
    size_t loff = (size_t)lane*16;
    #pragma unroll
    for (int u=0; u<4; u++){
        int nt = wave*4 + u;
        f32x4 c = {0,0,0,0};
        #pragma unroll
        for (int k8=0; k8<8; k8++){
            bf16x8 a = *(const bf16x8*)(arow + k8*32);
            bf16x8 b = *(const bf16x8*)((const char*)Bcmb + (size_t)(((nt<<4)+8+k8)<<10) + loff);
            c = MFMA(a, b, c, 0,0,0);
        }
        int n = (nt<<4) + (lane&15);
        #pragma unroll
        for (int q=0;q<4;q++) Gs[((lane>>4)<<2)+q][n] = f2bf(c[q]);
    }
    __syncthreads();
    bf16_t* dst = P + ((size_t)t*BATCH + b0)*HD;
    for (int i = tid; i < 512; i += 256){
        int r = i>>5, c = i&31;
        *(uint4*)(dst + (size_t)r*HD + c*8) = *(const uint4*)&Gs[r][c*8];
    }
}

// ---------------------------------------------------------------------------
// gru_step2: K-split GRU step. grid (64,4) x 512 (proven round 6). Decoder.
// ---------------------------------------------------------------------------
__global__ __launch_bounds__(512) void gru_step2(
    const bf16_t* __restrict__ A0, const bf16_t* __restrict__ A1,
    const bf16_t* __restrict__ Bp,
    const float* __restrict__ bih, const float* __restrict__ bhh,
    const float* __restrict__ hprev, float* __restrict__ hnext,
    bf16_t* __restrict__ hnext_bf, bf16_t* __restrict__ extra_bf)
{
    __shared__ __align__(16) bf16_t As[16][520];
    __shared__ __align__(16) f32x4 redR[4][64];
    __shared__ __align__(16) f32x4 redZ[4][64];
    __shared__ __align__(16) f32x4 redI[4][64];
    int tid = threadIdx.x, b0 = blockIdx.x*16;
    for (int i = tid; i < 1024; i += 512){
        int r = i>>6, c = i&63;
        const bf16_t* src = (c<32)? (A0 + (size_t)(b0+r)*HD + c*8)
                                  : (A1 + (size_t)(b0+r)*HD + (c-32)*8);
        *(uint4*)&As[r][c*8] = *(const uint4*)src;
    }
    __syncthreads();
    int lane = tid & 63, wave = tid >> 6;
    int pairId = wave >> 1, half = wave & 1;
    int jt = blockIdx.y*4 + pairId;
    const char* arow = (const char*)&As[lane&15][(lane>>4)*8];
    const char* bpc = (const char*)Bp;
    size_t loff = (size_t)lane*16;
    size_t offX = half ? (size_t)OFF_HN : (size_t)OFF_IN;
    int kt0 = half*8;
    f32x4 cr={0,0,0,0}, cz={0,0,0,0}, cx={0,0,0,0};
    #pragma unroll
    for (int k8=0; k8<8; k8++){
        int kt = kt0 + k8;
        bf16x8 a  = *(const bf16x8*)(arow + kt*64);
        bf16x8 br = *(const bf16x8*)(bpc + (size_t)(((jt<<4)+kt)<<10) + loff);
        bf16x8 bz = *(const bf16x8*)(bpc + OFF_Z + (size_t)(((jt<<4)+kt)<<10) + loff);
        bf16x8 bx = *(const bf16x8*)(bpc + offX + (size_t)(((jt<<3)+k8)<<10) + loff);
        cr = MFMA(a, br, cr, 0,0,0);
        cz = MFMA(a, bz, cz, 0,0,0);
        cx = MFMA(a, bx, cx, 0,0,0);
    }
    if (half == 0){
        redR[pairId][lane] = cr;
        redZ[pairId][lane] = cz;
        redI[pairId][lane] = cx;
    }
    __syncthreads();
    if (half == 1){
        f32x4 crA = redR[pairId][lane];
        f32x4 czA = redZ[pairId][lane];
        f32x4 ci  = redI[pairId][lane];
        int j = (jt<<4) + (lane&15);
        float b_r = bih[j] + bhh[j];
        float b_z = bih[256+j] + bhh[256+j];
        float b_i = bih[512+j], b_h = bhh[512+j];
        #pragma unroll
        for (int q=0;q<4;q++){
            int b = b0 + ((lane>>4)<<2) + q;
            float rv = sigm(cr[q] + crA[q] + b_r);
            float zv = sigm(cz[q] + czA[q] + b_z);
            float nv = tanhf(ci[q] + b_i + rv*(cx[q] + b_h));
            float h2 = (1.0f - zv)*nv + zv*hprev[(size_t)b*HD + j];
            hnext[(size_t)b*HD + j] = h2;
            bf16_t hb = f2bf(h2);
            hnext_bf[(size_t)b*HD + j] = hb;
            extra_bf[(size_t)b*HD + j] = hb;
        }
    }
}

// ---------------------------------------------------------------------------
// dec_front v7: 64 x 1024. Fuses logits + ys_{t-1} + softmax + ctx(P) + gfold.
// (verified round 8)
// ---------------------------------------------------------------------------
__global__ __launch_bounds__(1024) void dec_front(
    const bf16_t* __restrict__ hbf, const bf16_t* __restrict__ fxt,
    const bf16_t* __restrict__ P,
    const bf16_t* __restrict__ BL, const bf16_t* __restrict__ Bgf,
    const bf16_t* __restrict__ Bout,
    const float* __restrict__ lbp, const float* __restrict__ cbf,
    const float* __restrict__ outB,
    int t, bf16_t* __restrict__ g_out, float* __restrict__ out)
{
    __shared__ __align__(16) bf16_t As[16][296];   // [h(256) | fx(32)]
    __shared__ float awL[16][84];                  // logits -> aw
    __shared__ float Cpart[16][256];               // ctx partial (m 0..29)
    __shared__ float CbF[16][260];                 // ctx f32 (combined)

    int tid = threadIdx.x, b0 = blockIdx.x*16;

    // ---- stage As ----
    if (tid < 576){
        int r = tid/36, c = tid - r*36;
        const bf16_t* src = (c<32)? (hbf + (size_t)(b0+r)*HD + c*8)
                                  : (fxt + (size_t)(b0+r)*KIN + (c-32)*8);
        *(uint4*)&As[r][c*8] = *(const uint4*)src;
    }

    // ---- ctx geometry + issue-early prefetch from P ----
    int half = tid >> 9;              // 0: m 0..29, 1: m 30..59
    int u    = tid & 511;
    int cr_  = u >> 5;                // row 0..15
    int cc0  = (u & 31) * 8;          // col chunk
    const bf16_t* cbp = P + ((size_t)(half*30)*BATCH + (b0+cr_))*HD + cc0;
    u32x4 pf[10];
    #pragma unroll
    for (int i=0;i<10;i++) pf[i] = *(const u32x4*)(cbp + (size_t)i*BATCH*HD);

    __syncthreads();

    int lane = tid & 63, wave = tid >> 6;     // wave 0..15
    const bf16_t* arow = &As[lane&15][(lane>>4)*8];
    size_t loff = (size_t)lane*16;
    int kt0 = t ? 0 : 8;

    // ---- P1: 6 tiles (5 logits + ys), 1/wave ----
    if (wave < 5){
        f32x4 c = {0,0,0,0};
        #pragma unroll
        for (int kt = 0; kt < 9; kt++){
            bf16x8 a = *(const bf16x8*)(arow + kt*32);
            bf16x8 b = *(const bf16x8*)((const char*)BL + (size_t)((wave*9+kt)<<10) + loff);
            c = MFMA(a, b, c, 0,0,0);
        }
        int m = (wave<<4) + (lane&15);
        float bbm = lbp[m];
        #pragma unroll
        for (int q=0;q<4;q++) awL[((lane>>4)<<2)+q][m] = c[q] + bbm;
    } else if (wave == 5 && t > 0){
        f32x4 c = {0,0,0,0};
        #pragma unroll
        for (int kt = 0; kt < 8; kt++){
            bf16x8 a = *(const bf16x8*)(arow + kt*32);
            bf16x8 b = *(const bf16x8*)((const char*)Bout + (size_t)(kt<<10) + loff);
            c = MFMA(a, b, c, 0,0,0);
        }
        int o = lane & 15;
        float bo = outB[o];
        #pragma unroll
        for (int q=0;q<4;q++){
            int r = ((lane>>4)<<2) + q;
            out[((size_t)(t-1)*BATCH + b0+r)*KOUT + o] = c[q] + bo;
        }
    }
    __syncthreads();

    // ---- P2: softmax over awL rows ----
    if (tid < 256){
        int r2 = tid >> 4, l2 = tid & 15;
        float vmax = -1e30f;
        for (int m=l2; m<80; m+=16) vmax = fmaxf(vmax, awL[r2][m]);
        #pragma unroll
        for (int k=1; k<16; k<<=1) vmax = fmaxf(vmax, __shfl_xor(vmax, k, 16));
        float ps = 0.f;
        for (int m=l2; m<80; m+=16){ float v = __expf(awL[r2][m]-vmax); awL[r2][m]=v; ps += v; }
        #pragma unroll
        for (int k=1; k<16; k<<=1) ps += __shfl_xor(ps, k, 16);
        float inv = 1.0f/ps;
        for (int m=l2; m<80; m+=16) awL[r2][m] *= inv;
    }
    __syncthreads();

    // ---- P3a: partial ctx over P, each thread 30 m (10 prefetched) ----
    float acc[8];
    #pragma unroll
    for (int i=0;i<8;i++) acc[i] = 0.f;
    {
        const float* awr = &awL[cr_][half*30];
        #pragma unroll
        for (int i=0;i<10;i++){
            float w = awr[i];
            acc[0]=fmaf(w,bflo(pf[i][0]),acc[0]); acc[1]=fmaf(w,bfhi(pf[i][0]),acc[1]);
            acc[2]=fmaf(w,bflo(pf[i][1]),acc[2]); acc[3]=fmaf(w,bfhi(pf[i][1]),acc[3]);
            acc[4]=fmaf(w,bflo(pf[i][2]),acc[4]); acc[5]=fmaf(w,bfhi(pf[i][2]),acc[5]);
            acc[6]=fmaf(w,bflo(pf[i][3]),acc[6]); acc[7]=fmaf(w,bfhi(pf[i][3]),acc[7]);
        }
        #pragma unroll 5
        for (int i=10;i<30;i++){
            u32x4 v = *(const u32x4*)(cbp + (size_t)i*BATCH*HD);
            float w = awr[i];
            acc[0]=fmaf(w,bflo(v[0]),acc[0]); acc[1]=fmaf(w,bfhi(v[0]),acc[1]);
            acc[2]=fmaf(w,bflo(v[1]),acc[2]); acc[3]=fmaf(w,bfhi(v[1]),acc[3]);
            acc[4]=fmaf(w,bflo(v[2]),acc[4]); acc[5]=fmaf(w,bfhi(v[2]),acc[5]);
            acc[6]=fmaf(w,bflo(v[3]),acc[6]); acc[7]=fmaf(w,bfhi(v[3]),acc[7]);
        }
    }
    if (half == 0){
        float4 p0 = {acc[0],acc[1],acc[2],acc[3]};
        float4 p1 = {acc[4],acc[5],acc[6],acc[7]};
        *(float4*)&Cpart[cr_][cc0]   = p0;
        *(float4*)&Cpart[cr_][cc0+4] = p1;
    }
    __syncthreads();

    // ---- P3b: combine halves -> CbF f32 ----
    if (half == 1){
        float4 p0 = *(const float4*)&Cpart[cr_][cc0];
        float4 p1 = *(const float4*)&Cpart[cr_][cc0+4];
        float4 o0 = {acc[0]+p0.x, acc[1]+p0.y, acc[2]+p0.z, acc[3]+p0.w};
        float4 o1 = {acc[4]+p1.x, acc[5]+p1.y, acc[6]+p1.z, acc[7]+p1.w};
        *(float4*)&CbF[cr_][cc0]   = o0;
        *(float4*)&CbF[cr_][cc0+4] = o1;
    }
    __syncthreads();

    // ---- P4: g = tanh([h|fx]@Bgf + ctx + cbf), 1 tile/wave, K=9 kt ----
    {
        f32x4 c = {0,0,0,0};
        for (int kt=kt0; kt<9; kt++){
            bf16x8 a = *(const bf16x8*)(arow + kt*32);
            bf16x8 b = *(const bf16x8*)((const char*)Bgf + (size_t)((wave*9+kt)<<10) + loff);
            c = MFMA(a, b, c, 0,0,0);
        }
        int n = (wave<<4) + (lane&15);
        float bb = cbf[n];
        #pragma unroll
        for (int q=0;q<4;q++){
            int r = ((lane>>4)<<2) + q;
            g_out[(size_t)(b0+r)*HD + n] = f2bf(tanhf(c[q] + CbF[r][n] + bb));
        }
    }
}

// ---------------------------------------------------------------------------
// ys[79] = h_final(f32) @ outW^T + outB. grid 64x256.
// ---------------------------------------------------------------------------
__global__ __launch_bounds__(256) void final79(
    const float* __restrict__ hf, const float* __restrict__ outW,
    const float* __restrict__ outB, float* __restrict__ ys)
{
    __shared__ float hs[16][260];
    __shared__ float ow[16*260];
    int tid = threadIdx.x, b0 = blockIdx.x*16;
    for (int i=tid;i<4096;i+=256){ int o2=i>>8,k=i&255; ow[o2*260+k]=outW[(size_t)o2*HD+k]; }
    for (int i=tid;i<4096;i+=256){ int r=i>>8,k=i&255; hs[r][k]=hf[(size_t)(b0+r)*HD+k]; }
    __syncthreads();
    int r=tid>>4, o=tid&15;
    float acc=outB[o];
    const float* w=&ow[o*260];
    for(int k=0;k<256;k++) acc += hs[r][k]*w[k];
    ys[((size_t)79*BATCH + b0+r)*KOUT + o] = acc;
}

// ---------------------------------------------------------------------------
extern "C" void kernel_launch(void* const* d_in, const int* in_sizes, int n_in,
                              void* d_out, int out_size, void* d_ws, size_t ws_size,
                              hipStream_t stream) {
    const float* pre_x    = (const float*)d_in[0];
    const float* pre_y    = (const float*)d_in[1];
    const float* fwd_x    = (const float*)d_in[2];
    const float* enc_embW = (const float*)d_in[3];
    const float* enc_embB = (const float*)d_in[4];
    const float* enc_Wih  = (const float*)d_in[5];
    const float* enc_Whh  = (const float*)d_in[6];
    const float* enc_bih  = (const float*)d_in[7];
    const float* enc_bhh  = (const float*)d_in[8];
    const float* dec_embW = (const float*)d_in[9];
    const float* dec_embB = (const float*)d_in[10];
    const float* attn_W   = (const float*)d_in[11];
    const float* attn_b   = (const float*)d_in[12];
    const float* comb_W   = (const float*)d_in[13];
    const float* comb_b   = (const float*)d_in[14];
    const float* dec_Wih  = (const float*)d_in[15];
    const float* dec_Whh  = (const float*)d_in[16];
    const float* dec_bih  = (const float*)d_in[17];
    const float* dec_bhh  = (const float*)d_in[18];
    const float* out_W    = (const float*)d_in[19];
    const float* out_b    = (const float*)d_in[20];
    float* out = (float*)d_out;

    char* ws = (char*)d_ws;
    size_t o = 0;
    auto alloc = [&](size_t bytes)->char*{
        char* p = ws + o; o = (o + bytes + 255) & ~(size_t)255; return p;
    };
    bf16_t* EMB     = (bf16_t*)alloc((size_t)LPRE*BATCH*HD*2);     // 31.5 MB
    bf16_t* ENC_OUT = (bf16_t*)alloc((size_t)LPRE*BATCH*HD*2);     // 31.5 MB [t][B][H]
    bf16_t* PBUF    = (bf16_t*)alloc((size_t)LPRE*BATCH*HD*2);     // 31.5 MB P = enc@W2
    bf16_t* FXB     = (bf16_t*)alloc((size_t)LFWD*BATCH*KIN*2);
    float*  HF0     = (float*) alloc((size_t)BATCH*HD*4);
    float*  HF1     = (float*) alloc((size_t)BATCH*HD*4);
    bf16_t* HB0     = (bf16_t*)alloc((size_t)BATCH*HD*2);
    bf16_t* HB1     = (bf16_t*)alloc((size_t)BATCH*HD*2);
    bf16_t* GBUF    = (bf16_t*)alloc((size_t)BATCH*HD*2);
    bf16_t* DUMMY   = (bf16_t*)alloc((size_t)BATCH*HD*2);
    float*  WFUSE   = (float*) alloc((size_t)256*256*4);
    float*  EBIAS   = (float*) alloc(256*4);
    float*  LB      = (float*) alloc(80*4);
    float*  LB0     = (float*) alloc(80*4);
    float*  CBF     = (float*) alloc(256*4);
    float*  CBF0    = (float*) alloc(256*4);
    bf16_t* PACK_ENC = (bf16_t*)alloc(786432);
    bf16_t* PACK_DEC = (bf16_t*)alloc(786432);
    bf16_t* PACK_CMB = (bf16_t*)alloc(262144);
    bf16_t* PACK_GF  = (bf16_t*)alloc(147456);
    bf16_t* PACK_BL  = (bf16_t*)alloc(46080);
    bf16_t* PACK_BL0 = (bf16_t*)alloc(46080);
    bf16_t* PACK_OUT = (bf16_t*)alloc(8192);

    dim3 blk(256);
    // ---- prep (one-time) ----
    emb_kernel<<<dim3(64,60), blk, 0, stream>>>(pre_x, pre_y, enc_embW, enc_embB, EMB);
    fxconv<<<dim3(1280), blk, 0, stream>>>(fwd_x, FXB);
    pack_gru<<<dim3(192), blk, 0, stream>>>(enc_Wih, enc_Whh, PACK_ENC);
    pack_gru<<<dim3(192), blk, 0, stream>>>(dec_Wih, dec_Whh, PACK_DEC);
    pack_B512<<<dim3(64), blk, 0, stream>>>(comb_W, PACK_CMB);
    wfuse_kernel<<<dim3(257), blk, 0, stream>>>(dec_embW, dec_embB, out_W, out_b, WFUSE, EBIAS);
    pack_logits<<<dim3(24), blk, 0, stream>>>(WFUSE, dec_embW, attn_W, attn_b, dec_embB,
                                              EBIAS, PACK_BL, PACK_BL0, LB, LB0);
    pack_gfold<<<dim3(38), blk, 0, stream>>>(WFUSE, dec_embW, comb_W, comb_b,
                                             EBIAS, dec_embB, PACK_GF, CBF, CBF0);
    pack_out<<<dim3(2), blk, 0, stream>>>(out_W, PACK_OUT);

    // ---- encoder: ONE persistent dispatch (block-local recurrence) ----
    enc_persist<<<dim3(64), dim3(1024), 0, stream>>>(
        EMB, PACK_ENC, enc_bih, enc_bhh, HF0, HB0, ENC_OUT);

    // ---- P = ENC_OUT @ W2 (one-time, wide) ----
    pgemm<<<dim3(64,60), blk, 0, stream>>>(ENC_OUT, PACK_CMB, PBUF);

    float*  HF[2] = {HF0, HF1};
    bf16_t* HB[2] = {HB0, HB1};
    int p = 0;

    // ---- decoder: 2 dispatches per step ----
    for (int t = 0; t < LFWD; t++){
        const bf16_t* fxt = FXB + (size_t)t*BATCH*KIN;
        dec_front<<<dim3(64), dim3(1024), 0, stream>>>(
            HB[p], fxt, PBUF,
            t ? PACK_BL : PACK_BL0, PACK_GF, PACK_OUT,
            t ? LB : LB0, t ? CBF : CBF0, out_b,
            t, GBUF, out);
        gru_step2<<<dim3(64,4), dim3(512), 0, stream>>>(
            GBUF, HB[p], PACK_DEC, dec_bih, dec_bhh,
            HF[p], HF[p^1], HB[p^1], DUMMY);
        p ^= 1;
    }
    final79<<<dim3(64), blk, 0, stream>>>(HF[p], out_W, out_b, out);
}

// Round 13
// 2123.157 us; speedup vs baseline: 1.3048x; 1.3048x over previous
//
#include <hip/hip_runtime.h>
#include <hip/hip_bf16.h>

#define BATCH 1024
#define HD 256
#define MLEN 80
#define LPRE 60
#define LFWD 80
#define KIN 32
#define KOUT 16

typedef unsigned short bf16_t;
typedef __attribute__((ext_vector_type(8))) short bf16x8;
typedef __attribute__((ext_vector_type(4))) float f32x4;
typedef __attribute__((ext_vector_type(4))) unsigned u32x4;

#define MFMA __builtin_amdgcn_mfma_f32_16x16x32_bf16

__device__ __forceinline__ float bf2f(bf16_t v){ return __uint_as_float(((unsigned)v)<<16); }
__device__ __forceinline__ bf16_t f2bf(float f){
    unsigned u = __float_as_uint(f);
    return (bf16_t)((u + 0x7FFFu + ((u>>16)&1u)) >> 16);
}
__device__ __forceinline__ unsigned pack2(float lo, float hi){
    return (unsigned)f2bf(lo) | ((unsigned)f2bf(hi)<<16);
}
__device__ __forceinline__ float bflo(unsigned d){ return __uint_as_float(d<<16); }
__device__ __forceinline__ float bfhi(unsigned d){ return __uint_as_float(d & 0xffff0000u); }
__device__ __forceinline__ float sigm(float x){ return 1.0f/(1.0f+__expf(-x)); }

// Packed-B byte offsets inside a GRU weight pack (4 N-groups):
#define OFF_Z  262144
#define OFF_IN 524288
#define OFF_HN 655360

// ---------------------------------------------------------------------------
// Pack GRU weights: B[k][n] fragment-tiled bf16. grid 192x256
// ---------------------------------------------------------------------------
__global__ void pack_gru(const float* __restrict__ Wih, const float* __restrict__ Whh,
                         bf16_t* __restrict__ dst)
{
    int T = blockIdx.x*256 + threadIdx.x;   // < 49152
    int grp, local;
    if (T < 16384){ grp=0; local=T; }
    else if (T < 32768){ grp=1; local=T-16384; }
    else if (T < 40960){ grp=2; local=T-32768; }
    else { grp=3; local=T-40960; }
    int nkt = (grp<2)?16:8;
    int nt  = local / (nkt*64);
    int rem = local - nt*(nkt*64);
    int kt  = rem >> 6;
    int l   = rem & 63;
    int n   = nt*16 + (l&15);
    int k0  = kt*32 + ((l>>4)<<3);
    unsigned w[4];
    #pragma unroll
    for (int h2=0; h2<4; h2++){
        float v[2];
        #pragma unroll
        for (int s=0; s<2; s++){
            int k = k0 + h2*2 + s;
            if (grp==0)      v[s] = (k<256)? Wih[(size_t)n*HD + k]       : Whh[(size_t)n*HD + (k-256)];
            else if (grp==1) v[s] = (k<256)? Wih[(size_t)(256+n)*HD + k] : Whh[(size_t)(256+n)*HD + (k-256)];
            else if (grp==2) v[s] = Wih[(size_t)(512+n)*HD + k];
            else             v[s] = Whh[(size_t)(512+n)*HD + k];
        }
        w[h2] = pack2(v[0], v[1]);
    }
    uint4 u = {w[0],w[1],w[2],w[3]};
    *(uint4*)((char*)dst + (size_t)T*16) = u;
}

// ---------------------------------------------------------------------------
// Pack K=512,N=256 B from W[256][512] (combW): B[k][n]=W[n][k]. grid 64x256
// ---------------------------------------------------------------------------
__global__ void pack_B512(const float* __restrict__ W, bf16_t* __restrict__ dst)
{
    int T = blockIdx.x*256 + threadIdx.x;   // < 16384
    int nt = T >> 10, kt = (T>>6)&15, l = T&63;
    int n = nt*16 + (l&15);
    int k0 = kt*32 + ((l>>4)<<3);
    unsigned w[4];
    #pragma unroll
    for (int h2=0; h2<4; h2++)
        w[h2] = pack2(W[(size_t)n*512 + k0+h2*2], W[(size_t)n*512 + k0+h2*2+1]);
    uint4 u = {w[0],w[1],w[2],w[3]};
    *(uint4*)((char*)dst + (size_t)T*16) = u;
}

// ---------------------------------------------------------------------------
// Wfuse[k][n] = sum_o dembW[n][o]*outW[o][k]; e_bias[n]=dembB[n]+sum_o outB[o]*dembW[n][o]
// grid 257x256
// ---------------------------------------------------------------------------
__global__ void wfuse_kernel(const float* __restrict__ dembW, const float* __restrict__ dembB,
                             const float* __restrict__ outW, const float* __restrict__ outB,
                             float* __restrict__ Wfuse, float* __restrict__ ebias)
{
    int T = blockIdx.x*256 + threadIdx.x;
    if (T < 65536){
        int k = T >> 8, n = T & 255;
        float acc = 0.f;
        #pragma unroll
        for (int o=0;o<16;o++) acc += dembW[(size_t)n*48 + o]*outW[(size_t)o*HD + k];
        Wfuse[(size_t)k*HD + n] = acc;
    } else if (T < 65792){
        int n = T - 65536;
        float acc = dembB[n];
        #pragma unroll
        for (int o=0;o<16;o++) acc += outB[o]*dembW[(size_t)n*48 + o];
        ebias[n] = acc;
    }
}

// ---------------------------------------------------------------------------
// Pack logits B (t>=1 and t==0 variants) + bias vectors. grid 24x256.
// v11: loop-swapped + float4-vectorized (verified round 11).
// ---------------------------------------------------------------------------
__global__ void pack_logits(const float* __restrict__ Wfuse, const float* __restrict__ dembW,
                            const float* __restrict__ attW, const float* __restrict__ attB,
                            const float* __restrict__ dembB, const float* __restrict__ ebias,
                            bf16_t* __restrict__ BL, bf16_t* __restrict__ BL0,
                            float* __restrict__ lb, float* __restrict__ lb0)
{
    int T = blockIdx.x*256 + threadIdx.x;
    if (T < 5760){
        int variant = (T < 2880) ? 0 : 1;
        int local = variant ? (T-2880) : T;
        int nt = local/576, rem = local - nt*576;
        int kt = rem >> 6, l = rem & 63;
        int m  = nt*16 + (l&15);
        int k0 = kt*32 + ((l>>4)<<3);
        float acc[8];
        if (kt < 8){
            #pragma unroll
            for (int d=0;d<8;d++) acc[d] = attW[(size_t)m*512 + 256 + k0 + d];
            if (variant == 0){
                const float* ar = attW + (size_t)m*512;
                for (int n=0;n<256;n+=4){
                    float4 w = *(const float4*)(ar + n);
                    #pragma unroll
                    for (int d=0;d<8;d++){
                        float4 f = *(const float4*)(Wfuse + (size_t)(k0+d)*HD + n);
                        acc[d] = fmaf(f.x, w.x, acc[d]);
                        acc[d] = fmaf(f.y, w.y, acc[d]);
                        acc[d] = fmaf(f.z, w.z, acc[d]);
                        acc[d] = fmaf(f.w, w.w, acc[d]);
                    }
                }
            }
        } else {
            int kp0 = k0 - 256;
            #pragma unroll
            for (int d=0;d<8;d++) acc[d] = 0.f;
            const float* ar = attW + (size_t)m*512;
            for (int n=0;n<256;n++){
                float w = ar[n];
                const float* dr = dembW + (size_t)n*48 + 16 + kp0;
                float4 d0 = *(const float4*)dr;
                float4 d1 = *(const float4*)(dr+4);
                acc[0]=fmaf(d0.x,w,acc[0]); acc[1]=fmaf(d0.y,w,acc[1]);
                acc[2]=fmaf(d0.z,w,acc[2]); acc[3]=fmaf(d0.w,w,acc[3]);
                acc[4]=fmaf(d1.x,w,acc[4]); acc[5]=fmaf(d1.y,w,acc[5]);
                acc[6]=fmaf(d1.z,w,acc[6]); acc[7]=fmaf(d1.w,w,acc[7]);
            }
        }
        unsigned w4[4];
        #pragma unroll
        for (int h2=0;h2<4;h2++) w4[h2] = pack2(acc[h2*2], acc[h2*2+1]);
        uint4 u = {w4[0],w4[1],w4[2],w4[3]};
        bf16_t* d = variant ? BL0 : BL;
        *(uint4*)((char*)d + (size_t)local*16) = u;
    } else if (T < 5840){
        int m = T - 5760;
        float acc = attB[m];
        const float* ar = attW + (size_t)m*512;
        for (int n=0;n<256;n+=4){
            float4 w = *(const float4*)(ar + n);
            float4 e = *(const float4*)(ebias + n);
            acc = fmaf(e.x,w.x,acc); acc = fmaf(e.y,w.y,acc);
            acc = fmaf(e.z,w.z,acc); acc = fmaf(e.w,w.w,acc);
        }
        lb[m] = acc;
    } else if (T < 5920){
        int m = T - 5840;
        float acc = attB[m];
        const float* ar = attW + (size_t)m*512;
        for (int n=0;n<256;n+=4){
            float4 w = *(const float4*)(ar + n);
            float4 e = *(const float4*)(dembB + n);
            acc = fmaf(e.x,w.x,acc); acc = fmaf(e.y,w.y,acc);
            acc = fmaf(e.z,w.z,acc); acc = fmaf(e.w,w.w,acc);
        }
        lb0[m] = acc;
    }
}

// ---------------------------------------------------------------------------
// pack_gfold: Bgf[k][n] (K=288, 9 kt x 16 nt) = Be_src @ W1, fragment-packed.
// v11: loop-swapped + float4-vectorized (verified round 11).
// ---------------------------------------------------------------------------
__global__ void pack_gfold(const float* __restrict__ Wfuse, const float* __restrict__ dembW,
                           const float* __restrict__ combW, const float* __restrict__ combB,
                           const float* __restrict__ ebias, const float* __restrict__ dembB,
                           bf16_t* __restrict__ dst, float* __restrict__ cbf, float* __restrict__ cbf0)
{
    int T = blockIdx.x*256 + threadIdx.x;
    if (T < 9216){
        int nt = T/576, rem = T - nt*576;
        int kt = rem >> 6, l = rem & 63;
        int n = nt*16 + (l&15);
        int k0 = kt*32 + ((l>>4)<<3);
        float acc[8];
        #pragma unroll
        for (int d=0;d<8;d++) acc[d] = 0.f;
        const float* wr = combW + (size_t)n*512;
        if (kt < 8){
            for (int j=0;j<256;j+=4){
                float4 w = *(const float4*)(wr + j);
                #pragma unroll
                for (int d=0;d<8;d++){
                    float4 f = *(const float4*)(Wfuse + (size_t)(k0+d)*HD + j);
                    acc[d] = fmaf(f.x, w.x, acc[d]);
                    acc[d] = fmaf(f.y, w.y, acc[d]);
                    acc[d] = fmaf(f.z, w.z, acc[d]);
                    acc[d] = fmaf(f.w, w.w, acc[d]);
                }
            }
        } else {
            int kp0 = k0 - 256;
            for (int j=0;j<256;j++){
                float w = wr[j];
                const float* dr = dembW + (size_t)j*48 + 16 + kp0;
                float4 d0 = *(const float4*)dr;
                float4 d1 = *(const float4*)(dr+4);
                acc[0]=fmaf(d0.x,w,acc[0]); acc[1]=fmaf(d0.y,w,acc[1]);
                acc[2]=fmaf(d0.z,w,acc[2]); acc[3]=fmaf(d0.w,w,acc[3]);
                acc[4]=fmaf(d1.x,w,acc[4]); acc[5]=fmaf(d1.y,w,acc[5]);
                acc[6]=fmaf(d1.z,w,acc[6]); acc[7]=fmaf(d1.w,w,acc[7]);
            }
        }
        unsigned w4[4];
        #pragma unroll
        for (int h2=0;h2<4;h2++) w4[h2] = pack2(acc[h2*2], acc[h2*2+1]);
        uint4 u = {w4[0],w4[1],w4[2],w4[3]};
        *(uint4*)((char*)dst + (size_t)T*16) = u;
    } else if (T < 9472){
        int n = T - 9216;
        float acc = combB[n];
        const float* wr = combW + (size_t)n*512;
        for (int j=0;j<256;j+=4){
            float4 w = *(const float4*)(wr + j);
            float4 e = *(const float4*)(ebias + j);
            acc = fmaf(e.x,w.x,acc); acc = fmaf(e.y,w.y,acc);
            acc = fmaf(e.z,w.z,acc); acc = fmaf(e.w,w.w,acc);
        }
        cbf[n] = acc;
    } else if (T < 9728){
        int n = T - 9472;
        float acc = combB[n];
        const float* wr = combW + (size_t)n*512;
        for (int j=0;j<256;j+=4){
            float4 w = *(const float4*)(wr + j);
            float4 e = *(const float4*)(dembB + j);
            acc = fmaf(e.x,w.x,acc); acc = fmaf(e.y,w.y,acc);
            acc = fmaf(e.z,w.z,acc); acc = fmaf(e.w,w.w,acc);
        }
        cbf0[n] = acc;
    }
}

// ---------------------------------------------------------------------------
// Pack B_out [K=256][N=16] from outW[16][256]. grid 2x256
// ---------------------------------------------------------------------------
__global__ void pack_out(const float* __restrict__ outW, bf16_t* __restrict__ dst)
{
    int T = blockIdx.x*256 + threadIdx.x;   // < 512
    int kt = T >> 6, l = T & 63;
    int n  = l & 15;
    int k0 = kt*32 + ((l>>4)<<3);
    unsigned w[4];
    #pragma unroll
    for (int h2=0; h2<4; h2++)
        w[h2] = pack2(outW[(size_t)n*HD + k0+h2*2], outW[(size_t)n*HD + k0+h2*2+1]);
    uint4 u = {w[0],w[1],w[2],w[3]};
    *(uint4*)((char*)dst + (size_t)T*16) = u;
}

// ---------------------------------------------------------------------------
// All 60 encoder embeddings -> bf16. grid (64,60)x256
// ---------------------------------------------------------------------------
__global__ __launch_bounds__(256) void emb_kernel(
    const float* __restrict__ px, const float* __restrict__ py,
    const float* __restrict__ embW, const float* __restrict__ embB,
    bf16_t* __restrict__ emb)
{
    __shared__ float Ws[256*49];
    __shared__ float xy[16][48];
    __shared__ float bs[256];
    int t = blockIdx.y, b0 = blockIdx.x*16, tid = threadIdx.x;
    for (int i = tid; i < 256*48; i += 256){ int n=i/48, k=i-n*48; Ws[n*49+k]=embW[i]; }
    bs[tid] = embB[tid];
    for (int i = tid; i < 16*48; i += 256){
        int r=i/48, k=i-r*48;
        xy[r][k] = (k<KIN)? px[((size_t)t*BATCH + b0+r)*KIN + k]
                          : py[((size_t)t*BATCH + b0+r)*KOUT + (k-KIN)];
    }
    __syncthreads();
    int n = tid;
    const float* w = &Ws[n*49];
    for (int r=0;r<16;r++){
        float acc = bs[n];
        #pragma unroll
        for (int k=0;k<48;k++) acc += xy[r][k]*w[k];
        emb[((size_t)t*BATCH + b0+r)*HD + n] = f2bf(acc);
    }
}

// fx f32 -> bf16. grid 1280x256
__global__ void fxconv(const float* __restrict__ fx, bf16_t* __restrict__ dst)
{
    size_t i = (size_t)blockIdx.x*256 + threadIdx.x;
    const float4* s = (const float4*)(fx + i*8);
    float4 a = s[0], b = s[1];
    uint4 u = { pack2(a.x,a.y), pack2(a.z,a.w), pack2(b.x,b.y), pack2(b.z,b.w) };
    *(uint4*)(dst + i*8) = u;
}

// ---------------------------------------------------------------------------
// pgemm: P[t][b][n] = ENC_OUT[t][b][:] @ W2  (W2 = PACK_CMB kt 8..15).
// grid (64,60) x 256. (verified round 7/8)
// ---------------------------------------------------------------------------
__global__ __launch_bounds__(256) void pgemm(
    const bf16_t* __restrict__ enc, const bf16_t* __restrict__ Bcmb,
    bf16_t* __restrict__ P)
{
    __shared__ __align__(16) bf16_t As[16][264];
    __shared__ __align__(16) bf16_t Gs[16][264];
    int tid = threadIdx.x, b0 = blockIdx.x*16, t = blockIdx.y;
    const bf16_t* src = enc + ((size_t)t*BATCH + b0)*HD;
    for (int i = tid; i < 512; i += 256){
        int r = i>>5, c = i&31;
        *(uint4*)&As[r][c*8] = *(const uint4*)(src + (size_t)r*HD + c*8);
    }
    __syncthreads();
    int lane = tid&63, wave = tid>>6;
    const bf16_t* arow = &As[lane&15][(lane>>4)*8];
    size_t loff = (size_t)lane*16;
    #pragma unroll
    for (int u=0; u<4; u++){
        int nt = wave*4 + u;
        f32x4 c = {0,0,0,0};
        #pragma unroll
        for (int k8=0; k8<8; k8++){
            bf16x8 a = *(const bf16x8*)(arow + k8*32);
            bf16x8 b = *(const bf16x8*)((const char*)Bcmb + (size_t)(((nt<<4)+8+k8)<<10) + loff);
            c = MFMA(a, b, c, 0,0,0);
        }
        int n = (nt<<4) + (lane&15);
        #pragma unroll
        for (int q=0;q<4;q++) Gs[((lane>>4)<<2)+q][n] = f2bf(c[q]);
    }
    __syncthreads();
    bf16_t* dst = P + ((size_t)t*BATCH + b0)*HD;
    for (int i = tid; i < 512; i += 256){
        int r = i>>5, c = i&31;
        *(uint4*)(dst + (size_t)r*HD + c*8) = *(const uint4*)&Gs[r][c*8];
    }
}

// ---------------------------------------------------------------------------
// gru_step2: K-split GRU step. grid (64,4) x 512 (proven round 6).
// ---------------------------------------------------------------------------
__global__ __launch_bounds__(512) void gru_step2(
    const bf16_t* __restrict__ A0, const bf16_t* __restrict__ A1,
    const bf16_t* __restrict__ Bp,
    const float* __restrict__ bih, const float* __restrict__ bhh,
    const float* __restrict__ hprev, float* __restrict__ hnext,
    bf16_t* __restrict__ hnext_bf, bf16_t* __restrict__ extra_bf)
{
    __shared__ __align__(16) bf16_t As[16][520];
    __shared__ __align__(16) f32x4 redR[4][64];
    __shared__ __align__(16) f32x4 redZ[4][64];
    __shared__ __align__(16) f32x4 redI[4][64];
    int tid = threadIdx.x, b0 = blockIdx.x*16;
    for (int i = tid; i < 1024; i += 512){
        int r = i>>6, c = i&63;
        const bf16_t* src = (c<32)? (A0 + (size_t)(b0+r)*HD + c*8)
                                  : (A1 + (size_t)(b0+r)*HD + (c-32)*8);
        *(uint4*)&As[r][c*8] = *(const uint4*)src;
    }
    __syncthreads();
    int lane = tid & 63, wave = tid >> 6;
    int pairId = wave >> 1, half = wave & 1;
    int jt = blockIdx.y*4 + pairId;
    const char* arow = (const char*)&As[lane&15][(lane>>4)*8];
    const char* bpc = (const char*)Bp;
    size_t loff = (size_t)lane*16;
    size_t offX = half ? (size_t)OFF_HN : (size_t)OFF_IN;
    int kt0 = half*8;
    f32x4 cr={0,0,0,0}, cz={0,0,0,0}, cx={0,0,0,0};
    #pragma unroll
    for (int k8=0; k8<8; k8++){
        int kt = kt0 + k8;
        bf16x8 a  = *(const bf16x8*)(arow + kt*64);
        bf16x8 br = *(const bf16x8*)(bpc + (size_t)(((jt<<4)+kt)<<10) + loff);
        bf16x8 bz = *(const bf16x8*)(bpc + OFF_Z + (size_t)(((jt<<4)+kt)<<10) + loff);
        bf16x8 bx = *(const bf16x8*)(bpc + offX + (size_t)(((jt<<3)+k8)<<10) + loff);
        cr = MFMA(a, br, cr, 0,0,0);
        cz = MFMA(a, bz, cz, 0,0,0);
        cx = MFMA(a, bx, cx, 0,0,0);
    }
    if (half == 0){
        redR[pairId][lane] = cr;
        redZ[pairId][lane] = cz;
        redI[pairId][lane] = cx;
    }
    __syncthreads();
    if (half == 1){
        f32x4 crA = redR[pairId][lane];
        f32x4 czA = redZ[pairId][lane];
        f32x4 ci  = redI[pairId][lane];
        int j = (jt<<4) + (lane&15);
        float b_r = bih[j] + bhh[j];
        float b_z = bih[256+j] + bhh[256+j];
        float b_i = bih[512+j], b_h = bhh[512+j];
        #pragma unroll
        for (int q=0;q<4;q++){
            int b = b0 + ((lane>>4)<<2) + q;
            float rv = sigm(cr[q] + crA[q] + b_r);
            float zv = sigm(cz[q] + czA[q] + b_z);
            float nv = tanhf(ci[q] + b_i + rv*(cx[q] + b_h));
            float h2 = (1.0f - zv)*nv + zv*hprev[(size_t)b*HD + j];
            hnext[(size_t)b*HD + j] = h2;
            bf16_t hb = f2bf(h2);
            hnext_bf[(size_t)b*HD + j] = hb;
            extra_bf[(size_t)b*HD + j] = hb;
        }
    }
}

// ---------------------------------------------------------------------------
// dec_front2: grid (64,2) x 1024. Column-split: block y owns 128 output cols.
// P1 logits + P2 softmax computed REDUNDANTLY in both y-blocks (deterministic,
// LDS-local; round-9-proven trick) -> no aw exchange. ctx reads only y's half
// of P (halves per-CU BW demand); P4 computes y's 8 gfold tiles. ys in y=0.
// Math identical to verified round-8 dec_front.
// ---------------------------------------------------------------------------
__global__ __launch_bounds__(1024) void dec_front2(
    const bf16_t* __restrict__ hbf, const bf16_t* __restrict__ fxt,
    const bf16_t* __restrict__ P,
    const bf16_t* __restrict__ BL, const bf16_t* __restrict__ Bgf,
    const bf16_t* __restrict__ Bout,
    const float* __restrict__ lbp, const float* __restrict__ cbf,
    const float* __restrict__ outB,
    int t, bf16_t* __restrict__ g_out, float* __restrict__ out)
{
    __shared__ __align__(16) bf16_t As[16][296];   // [h(256) | fx(32)]
    __shared__ float awL[16][84];                  // logits -> aw
    __shared__ float Cpart[16][128];               // ctx partial (m 0..29), y's cols
    __shared__ float CbF[16][132];                 // ctx f32 combined, y's cols

    int tid = threadIdx.x, b0 = blockIdx.x*16, y = blockIdx.y;

    // ---- stage As ----
    if (tid < 576){
        int r = tid/36, c = tid - r*36;
        const bf16_t* src = (c<32)? (hbf + (size_t)(b0+r)*HD + c*8)
                                  : (fxt + (size_t)(b0+r)*KIN + (c-32)*8);
        *(uint4*)&As[r][c*8] = *(const uint4*)src;
    }

    // ---- ctx geometry + issue-early prefetch from P (y's 128-col slice) ----
    int half = tid >> 9;              // 0: m 0..29, 1: m 30..59
    int u    = tid & 511;
    int cr_  = u >> 5;                // row 0..15
    int cl4  = (u & 31) * 4;          // local col chunk (4 cols, uint2)
    const bf16_t* cbp = P + ((size_t)(half*30)*BATCH + (b0+cr_))*HD + y*128 + cl4;
    uint2 pf[10];
    #pragma unroll
    for (int i=0;i<10;i++) pf[i] = *(const uint2*)(cbp + (size_t)i*BATCH*HD);

    __syncthreads();

    int lane = tid & 63, wave = tid >> 6;     // wave 0..15
    const bf16_t* arow = &As[lane&15][(lane>>4)*8];
    size_t loff = (size_t)lane*16;
    int kt0 = t ? 0 : 8;

    // ---- P1: logits (waves 0-4, both blocks); ys (y=0, wave 5) ----
    if (wave < 5){
        f32x4 c = {0,0,0,0};
        #pragma unroll
        for (int kt = 0; kt < 9; kt++){
            bf16x8 a = *(const bf16x8*)(arow + kt*32);
            bf16x8 b = *(const bf16x8*)((const char*)BL + (size_t)((wave*9+kt)<<10) + loff);
            c = MFMA(a, b, c, 0,0,0);
        }
        int m = (wave<<4) + (lane&15);
        float bbm = lbp[m];
        #pragma unroll
        for (int q=0;q<4;q++) awL[((lane>>4)<<2)+q][m] = c[q] + bbm;
    } else if (wave == 5 && y == 0 && t > 0){
        f32x4 c = {0,0,0,0};
        #pragma unroll
        for (int kt = 0; kt < 8; kt++){
            bf16x8 a = *(const bf16x8*)(arow + kt*32);
            bf16x8 b = *(const bf16x8*)((const char*)Bout + (size_t)(kt<<10) + loff);
            c = MFMA(a, b, c, 0,0,0);
        }
        int o = lane & 15;
        float bo = outB[o];
        #pragma unroll
        for (int q=0;q<4;q++){
            int r = ((lane>>4)<<2) + q;
            out[((size_t)(t-1)*BATCH + b0+r)*KOUT + o] = c[q] + bo;
        }
    }
    __syncthreads();

    // ---- P2: softmax (redundant per block, identical result) ----
    if (tid < 256){
        int r2 = tid >> 4, l2 = tid & 15;
        float vmax = -1e30f;
        for (int m=l2; m<80; m+=16) vmax = fmaxf(vmax, awL[r2][m]);
        #pragma unroll
        for (int k=1; k<16; k<<=1) vmax = fmaxf(vmax, __shfl_xor(vmax, k, 16));
        float ps = 0.f;
        for (int m=l2; m<80; m+=16){ float v = __expf(awL[r2][m]-vmax); awL[r2][m]=v; ps += v; }
        #pragma unroll
        for (int k=1; k<16; k<<=1) ps += __shfl_xor(ps, k, 16);
        float inv = 1.0f/ps;
        for (int m=l2; m<80; m+=16) awL[r2][m] *= inv;
    }
    __syncthreads();

    // ---- P3a: partial ctx over y's slice of P; 30 m/thread (10 prefetched) ----
    float a0=0.f, a1=0.f, a2=0.f, a3=0.f;
    {
        const float* awr = &awL[cr_][half*30];
        #pragma unroll
        for (int i=0;i<10;i++){
            float w = awr[i];
            a0=fmaf(w,bflo(pf[i].x),a0); a1=fmaf(w,bfhi(pf[i].x),a1);
            a2=fmaf(w,bflo(pf[i].y),a2); a3=fmaf(w,bfhi(pf[i].y),a3);
        }
        #pragma unroll 5
        for (int i=10;i<30;i++){
            uint2 v = *(const uint2*)(cbp + (size_t)i*BATCH*HD);
            float w = awr[i];
            a0=fmaf(w,bflo(v.x),a0); a1=fmaf(w,bfhi(v.x),a1);
            a2=fmaf(w,bflo(v.y),a2); a3=fmaf(w,bfhi(v.y),a3);
        }
    }
    if (half == 0){
        float4 p = {a0,a1,a2,a3};
        *(float4*)&Cpart[cr_][cl4] = p;
    }
    __syncthreads();

    // ---- P3b: combine halves -> CbF f32 ----
    if (half == 1){
        float4 p = *(const float4*)&Cpart[cr_][cl4];
        float4 o0 = {a0+p.x, a1+p.y, a2+p.z, a3+p.w};
        *(float4*)&CbF[cr_][cl4] = o0;
    }
    __syncthreads();

    // ---- P4: g = tanh([h|fx]@Bgf + ctx + cbf); 8 tiles, waves 0-7 ----
    if (wave < 8){
        int nt = y*8 + wave;
        f32x4 c = {0,0,0,0};
        for (int kt=kt0; kt<9; kt++){
            bf16x8 a = *(const bf16x8*)(arow + kt*32);
            bf16x8 b = *(const bf16x8*)((const char*)Bgf + (size_t)((nt*9+kt)<<10) + loff);
            c = MFMA(a, b, c, 0,0,0);
        }
        int n  = (nt<<4) + (lane&15);           // global col
        int nl = (wave<<4) + (lane&15);         // local col within y's 128
        float bb = cbf[n];
        #pragma unroll
        for (int q=0;q<4;q++){
            int r = ((lane>>4)<<2) + q;
            g_out[(size_t)(b0+r)*HD + n] = f2bf(tanhf(c[q] + CbF[r][nl] + bb));
        }
    }
}

// ---------------------------------------------------------------------------
// ys[79] = h_final(f32) @ outW^T + outB. grid 64x256.
// ---------------------------------------------------------------------------
__global__ __launch_bounds__(256) void final79(
    const float* __restrict__ hf, const float* __restrict__ outW,
    const float* __restrict__ outB, float* __restrict__ ys)
{
    __shared__ float hs[16][260];
    __shared__ float ow[16*260];
    int tid = threadIdx.x, b0 = blockIdx.x*16;
    for (int i=tid;i<4096;i+=256){ int o2=i>>8,k=i&255; ow[o2*260+k]=outW[(size_t)o2*HD+k]; }
    for (int i=tid;i<4096;i+=256){ int r=i>>8,k=i&255; hs[r][k]=hf[(size_t)(b0+r)*HD+k]; }
    __syncthreads();
    int r=tid>>4, o=tid&15;
    float acc=outB[o];
    const float* w=&ow[o*260];
    for(int k=0;k<256;k++) acc += hs[r][k]*w[k];
    ys[((size_t)79*BATCH + b0+r)*KOUT + o] = acc;
}

// ---------------------------------------------------------------------------
extern "C" void kernel_launch(void* const* d_in, const int* in_sizes, int n_in,
                              void* d_out, int out_size, void* d_ws, size_t ws_size,
                              hipStream_t stream) {
    const float* pre_x    = (const float*)d_in[0];
    const float* pre_y    = (const float*)d_in[1];
    const float* fwd_x    = (const float*)d_in[2];
    const float* enc_embW = (const float*)d_in[3];
    const float* enc_embB = (const float*)d_in[4];
    const float* enc_Wih  = (const float*)d_in[5];
    const float* enc_Whh  = (const float*)d_in[6];
    const float* enc_bih  = (const float*)d_in[7];
    const float* enc_bhh  = (const float*)d_in[8];
    const float* dec_embW = (const float*)d_in[9];
    const float* dec_embB = (const float*)d_in[10];
    const float* attn_W   = (const float*)d_in[11];
    const float* attn_b   = (const float*)d_in[12];
    const float* comb_W   = (const float*)d_in[13];
    const float* comb_b   = (const float*)d_in[14];
    const float* dec_Wih  = (const float*)d_in[15];
    const float* dec_Whh  = (const float*)d_in[16];
    const float* dec_bih  = (const float*)d_in[17];
    const float* dec_bhh  = (const float*)d_in[18];
    const float* out_W    = (const float*)d_in[19];
    const float* out_b    = (const float*)d_in[20];
    float* out = (float*)d_out;

    char* ws = (char*)d_ws;
    size_t o = 0;
    auto alloc = [&](size_t bytes)->char*{
        char* p = ws + o; o = (o + bytes + 255) & ~(size_t)255; return p;
    };
    bf16_t* EMB     = (bf16_t*)alloc((size_t)LPRE*BATCH*HD*2);     // 31.5 MB
    bf16_t* ENC_OUT = (bf16_t*)alloc((size_t)LPRE*BATCH*HD*2);     // 31.5 MB [t][B][H]
    bf16_t* PBUF    = (bf16_t*)alloc((size_t)LPRE*BATCH*HD*2);     // 31.5 MB P = enc@W2
    bf16_t* FXB     = (bf16_t*)alloc((size_t)LFWD*BATCH*KIN*2);
    float*  HF0     = (float*) alloc((size_t)BATCH*HD*4);
    float*  HF1     = (float*) alloc((size_t)BATCH*HD*4);
    bf16_t* HB0     = (bf16_t*)alloc((size_t)BATCH*HD*2);
    bf16_t* HB1     = (bf16_t*)alloc((size_t)BATCH*HD*2);
    bf16_t* GBUF    = (bf16_t*)alloc((size_t)BATCH*HD*2);
    bf16_t* DUMMY   = (bf16_t*)alloc((size_t)BATCH*HD*2);
    float*  WFUSE   = (float*) alloc((size_t)256*256*4);
    float*  EBIAS   = (float*) alloc(256*4);
    float*  LB      = (float*) alloc(80*4);
    float*  LB0     = (float*) alloc(80*4);
    float*  CBF     = (float*) alloc(256*4);
    float*  CBF0    = (float*) alloc(256*4);
    bf16_t* PACK_ENC = (bf16_t*)alloc(786432);
    bf16_t* PACK_DEC = (bf16_t*)alloc(786432);
    bf16_t* PACK_CMB = (bf16_t*)alloc(262144);
    bf16_t* PACK_GF  = (bf16_t*)alloc(147456);
    bf16_t* PACK_BL  = (bf16_t*)alloc(46080);
    bf16_t* PACK_BL0 = (bf16_t*)alloc(46080);
    bf16_t* PACK_OUT = (bf16_t*)alloc(8192);

    hipMemsetAsync(HF0, 0, (size_t)BATCH*HD*4, stream);
    hipMemsetAsync(HB0, 0, (size_t)BATCH*HD*2, stream);

    dim3 blk(256);
    // ---- prep (one-time) ----
    emb_kernel<<<dim3(64,60), blk, 0, stream>>>(pre_x, pre_y, enc_embW, enc_embB, EMB);
    fxconv<<<dim3(1280), blk, 0, stream>>>(fwd_x, FXB);
    pack_gru<<<dim3(192), blk, 0, stream>>>(enc_Wih, enc_Whh, PACK_ENC);
    pack_gru<<<dim3(192), blk, 0, stream>>>(dec_Wih, dec_Whh, PACK_DEC);
    pack_B512<<<dim3(64), blk, 0, stream>>>(comb_W, PACK_CMB);
    wfuse_kernel<<<dim3(257), blk, 0, stream>>>(dec_embW, dec_embB, out_W, out_b, WFUSE, EBIAS);
    pack_logits<<<dim3(24), blk, 0, stream>>>(WFUSE, dec_embW, attn_W, attn_b, dec_embB,
                                              EBIAS, PACK_BL, PACK_BL0, LB, LB0);
    pack_gfold<<<dim3(38), blk, 0, stream>>>(WFUSE, dec_embW, comb_W, comb_b,
                                             EBIAS, dec_embB, PACK_GF, CBF, CBF0);
    pack_out<<<dim3(2), blk, 0, stream>>>(out_W, PACK_OUT);

    float*  HF[2] = {HF0, HF1};
    bf16_t* HB[2] = {HB0, HB1};
    int p = 0;

    // ---- encoder: 60 gru_step2 dispatches (proven shape) ----
    for (int t = 0; t < LPRE; t++){
        gru_step2<<<dim3(64,4), dim3(512), 0, stream>>>(
            EMB + (size_t)t*BATCH*HD, HB[p], PACK_ENC, enc_bih, enc_bhh,
            HF[p], HF[p^1], HB[p^1], ENC_OUT + (size_t)t*BATCH*HD);
        p ^= 1;
    }
    // ---- P = ENC_OUT @ W2 (one-time, wide) ----
    pgemm<<<dim3(64,60), blk, 0, stream>>>(ENC_OUT, PACK_CMB, PBUF);

    // ---- decoder: 2 dispatches per step; front column-split over 128 blocks ----
    for (int t = 0; t < LFWD; t++){
        const bf16_t* fxt = FXB + (size_t)t*BATCH*KIN;
        dec_front2<<<dim3(64,2), dim3(1024), 0, stream>>>(
            HB[p], fxt, PBUF,
            t ? PACK_BL : PACK_BL0, PACK_GF, PACK_OUT,
            t ? LB : LB0, t ? CBF : CBF0, out_b,
            t, GBUF, out);
        gru_step2<<<dim3(64,4), dim3(512), 0, stream>>>(
            GBUF, HB[p], PACK_DEC, dec_bih, dec_bhh,
            HF[p], HF[p^1], HB[p^1], DUMMY);
        p ^= 1;
    }
    final79<<<dim3(64), blk, 0, stream>>>(HF[p], out_W, out_b, out);
}